// Round 1
// baseline (177.134 us; speedup 1.0000x reference)
//
#include <hip/hip_runtime.h>
#include <hip/hip_bf16.h>

// R9: full fusion. One kernel per 16-px m-tile does x-load + BN/ReLU + 2x2
// pool + pack-to-fragment-LDS + MFMA GEMM + store. Eliminates the 12.8 MB
// ysw intermediate (write+read) and the 1.5-block/CU latency-bound stage2.
// W is pre-swizzled to bf16 fragment order by a tiny 32-block kernel (256 KB
// workspace), then streamed from L2 by every block (proven R7 pattern).

typedef short bf16x8 __attribute__((ext_vector_type(8)));
typedef float f32x4  __attribute__((ext_vector_type(4)));

constexpr int CIN = 512, COUT = 256, HH = 56, WW = 56, HP = 28, WP = 28;
constexpr int PP = HP * WP;        // 784 pooled px per plane
constexpr int RT = PP / 16;        // 49 m-tiles per image

__device__ __forceinline__ short f2bf(float f) {
    __hip_bfloat16 h = __float2bfloat16(f);
    return *reinterpret_cast<short*>(&h);
}

// Fragment-order layouts (verified R2-R8):
//   wsw[(ot*16+ksg)*64 + lane] : W[o=ot*16+(lane&15)][k=ksg*32+(lane>>4)*8+j]
//   Yl [ksg*64 + lane]         : y[m=(lane&15)      ][k=ksg*32+(lane>>4)*8+j]

__global__ __launch_bounds__(512)
void wcvt(const float* __restrict__ w, short* __restrict__ wsw)
{
    int t    = blockIdx.x * 512 + threadIdx.x;   // [0, 16384)
    int lane = t & 63;
    int tile = t >> 6;                           // ot*16 + ksg
    int o    = (tile >> 4) * 16 + (lane & 15);
    int k    = (tile & 15) * 32 + (lane >> 4) * 8;
    const float4* src = reinterpret_cast<const float4*>(w + (size_t)o * CIN + k);
    float4 v0 = src[0], v1 = src[1];
    bf16x8 p;
    p[0]=f2bf(v0.x); p[1]=f2bf(v0.y); p[2]=f2bf(v0.z); p[3]=f2bf(v0.w);
    p[4]=f2bf(v1.x); p[5]=f2bf(v1.y); p[6]=f2bf(v1.z); p[7]=f2bf(v1.w);
    reinterpret_cast<bf16x8*>(wsw)[t] = p;
}

__global__ __launch_bounds__(256, 3)
void fused(const float* __restrict__ x,  const float* __restrict__ bnw,
           const float* __restrict__ bnb, const float* __restrict__ bnm,
           const float* __restrict__ bnv, const short* __restrict__ wsw,
           float* __restrict__ out)
{
    __shared__ bf16x8 Yl[16 * 64];     // 16 KB fragment-order y tile
    __shared__ float2 sct[CIN];        // 4 KB (scale, shift) per channel

    const int tid = threadIdx.x;
    const int mt  = blockIdx.x;        // 0..783
    const int b   = mt / RT;           // image
    const int r   = mt - b * RT;       // m-tile within pooled plane

    // BN coefficients -> LDS (2 channels per thread)
    {
        int c = tid * 2;
        float sc0 = bnw[c]     * rsqrtf(bnv[c]     + 1e-5f);
        float sc1 = bnw[c + 1] * rsqrtf(bnv[c + 1] + 1e-5f);
        sct[c]     = make_float2(sc0, bnb[c]     - bnm[c]     * sc0);
        sct[c + 1] = make_float2(sc1, bnb[c + 1] - bnm[c + 1] * sc1);
    }
    __syncthreads();

    // ---- Phase A: gather x, BN+ReLU, 2x2 pool, pack to fragment LDS ----
    // Thread owns one pooled-px pair (float4 spans both, never crosses a raw
    // row since p0 is even) x 8 channels x 2 passes.
    const int pair = tid & 7;                    // px pair in tile, 0..7
    const int p0   = r * 16 + pair * 2;          // even pooled px
    const int hp   = p0 / WP, wp = p0 - hp * WP; // wp even -> 16B aligned
    const size_t rowoff = (size_t)(2 * hp) * WW + 2 * wp;

    #pragma unroll
    for (int pass = 0; pass < 2; pass++) {
        const int cg = pass * 32 + (tid >> 3);   // 8-channel group, 0..63
        const int c0 = cg * 8;
        const float* bp = x + ((size_t)b * CIN + c0) * (HH * WW) + rowoff;
        bf16x8 pk0, pk1;
        #pragma unroll
        for (int j = 0; j < 8; j++) {
            const float* cp = bp + (size_t)j * (HH * WW);
            float4 lo = *reinterpret_cast<const float4*>(cp);       // raw row 2hp
            float4 hi = *reinterpret_cast<const float4*>(cp + WW);  // raw row 2hp+1
            float2 s  = sct[c0 + j];
            float y0 = (fmaxf(fmaf(lo.x, s.x, s.y), 0.f) + fmaxf(fmaf(lo.y, s.x, s.y), 0.f)
                      + fmaxf(fmaf(hi.x, s.x, s.y), 0.f) + fmaxf(fmaf(hi.y, s.x, s.y), 0.f)) * 0.25f;
            float y1 = (fmaxf(fmaf(lo.z, s.x, s.y), 0.f) + fmaxf(fmaf(lo.w, s.x, s.y), 0.f)
                      + fmaxf(fmaf(hi.z, s.x, s.y), 0.f) + fmaxf(fmaf(hi.w, s.x, s.y), 0.f)) * 0.25f;
            pk0[j] = f2bf(y0);
            pk1[j] = f2bf(y1);
        }
        // k = c0 + j = ksg*32 + sub*8 + j ; m = px16 -> fragment slot sub*16+px
        const int ksg = cg >> 2, sub = cg & 3;
        Yl[ksg * 64 + sub * 16 + pair * 2    ] = pk0;
        Yl[ksg * 64 + sub * 16 + pair * 2 + 1] = pk1;
    }
    __syncthreads();                   // sole data barrier

    // ---- Phase B: fragment GEMM, W streamed from L2 (zero extra LDS) ----
    const int lane = tid & 63, wv = tid >> 6;    // wave -> 64 outputs
    const int l16  = lane & 15, q = lane >> 4;
    const bf16x8* wfp = reinterpret_cast<const bf16x8*>(wsw);

    f32x4 acc[4];
    #pragma unroll
    for (int ns = 0; ns < 4; ns++) acc[ns] = (f32x4){0.f, 0.f, 0.f, 0.f};

    #pragma unroll
    for (int ksg = 0; ksg < 16; ksg++) {
        bf16x8 yf = Yl[ksg * 64 + lane];         // linear ds_read_b128
        #pragma unroll
        for (int ns = 0; ns < 4; ns++) {
            bf16x8 wf = wfp[(size_t)((wv * 4 + ns) * 16 + ksg) * 64 + lane];
            acc[ns] = __builtin_amdgcn_mfma_f32_16x16x32_bf16(wf, yf, acc[ns], 0, 0, 0);
        }
    }

    // Epilogue: D col = m = l16 -> 64B full-line stores per 16-lane cluster
    const int addrm = b * (COUT * PP) + r * 16 + l16;
    #pragma unroll
    for (int ns = 0; ns < 4; ns++)
        #pragma unroll
        for (int rg = 0; rg < 4; rg++) {
            int o = wv * 64 + ns * 16 + q * 4 + rg;
            out[(size_t)addrm + (size_t)o * PP] = acc[ns][rg];
        }
}

extern "C" void kernel_launch(void* const* d_in, const int* in_sizes, int n_in,
                              void* d_out, int out_size, void* d_ws, size_t ws_size,
                              hipStream_t stream) {
    const float* x   = (const float*)d_in[0];
    const float* bnw = (const float*)d_in[1];
    const float* bnb = (const float*)d_in[2];
    const float* bnm = (const float*)d_in[3];
    const float* bnv = (const float*)d_in[4];
    const float* w   = (const float*)d_in[5];
    float* out = (float*)d_out;

    short* wsw = (short*)d_ws;                   // 256 KB bf16 fragment-order W

    wcvt <<<32, 512, 0, stream>>>(w, wsw);
    fused<<<16 * RT, 256, 0, stream>>>(x, bnw, bnb, bnm, bnv, wsw, out);
}